// Round 9
// baseline (74.600 us; speedup 1.0000x reference)
//
#include <hip/hip_runtime.h>
#include <stdint.h>

#define NQ 14
#define DIM 16384
#define NL 6
#define NBATCH 1024
#define PI_F 3.14159265358979323846f
#define BLOCK 512

// ================= constexpr GF(2) circuit algebra =================
// Verified end-to-end (rounds 2/5/7: absmax 0.0).  CNOT chain = I+S.
// After l chains, gate on bit p pairs i with i^mcol(l,p); side-0 selected by
// parity(i & grow(l,p)).  Lucas: C(l,k) odd iff (k & ~l)==0.
constexpr uint32_t mcol(int l, int p) {          // column p of (I+S)^l
    uint32_t m = 0;
    for (int k = 0; k <= p; ++k) if ((k & ~l) == 0) m ^= 1u << (p - k);
    return m;
}
constexpr uint32_t grow(int l, int p) {          // row p of U^l = (I+S)^(16-l)
    uint32_t g = 0;
    const int e = 16 - l;
    for (int k = 0; k + p < NQ; ++k) if ((k & ~e) == 0) g ^= 1u << (p + k);
    return g;
}
constexpr uint32_t popb(uint32_t x) { uint32_t c = 0; while (x) { c += x & 1u; x >>= 1; } return c; }
constexpr int msbit(uint32_t m) { int b = 0; while (m >> (b + 1)) ++b; return b; }
// Bank swizzle: fold bits 5..7 ^ 8..10 ^ 11..13 into the 16B-column bits 2..4.
// Bijective (triangular). Verified per layer: every 8-lane group's varying
// mask triple has fold-rank>=2 -> <=2-way LDS access (free, m136).
constexpr uint32_t PIW(uint32_t x) {
    return x ^ ((((x >> 5) ^ (x >> 8) ^ (x >> 11)) & 7u) << 2);
}

// 4 groups per layer: p ranges {0..4}, {5..7}, {8..10}, {11..13}
constexpr int pbx(int grp) { return grp == 0 ? 0 : (grp == 1 ? 5 : (grp == 2 ? 8 : 11)); }
template<int GRP> constexpr int ngates() { return GRP == 0 ? 5 : 3; }

// register hi dims (4-aligned): G0 -> hi parts of gates p2..4; G1/2/3 -> own h's
constexpr uint32_t mhvx(int l, int grp, int j) {
    return grp == 0 ? (mcol(l, 2 + j) & ~3u) : (mcol(l, pbx(grp) + j) & ~3u);
}
template<int L, int GRP, int J> constexpr uint32_t mhv() { return mhvx(L, GRP, J); }

// thread-base basis: tid bit j -> quad-space vector.
// G0: units e5..e13 (cross-wave layout, barrier transitions).
// G1/G2/G3: lanes (bits 0..5) = the OTHER two h-triples -> wave-closure:
//   span(lane)+span(reg-hi) = span{h5..h13} identical for G1/G2/G3;
//   block dims (bits 6..8) = e2,e3,e4 shared -> G1->G2->G3 are wave-local.
constexpr uint32_t tbb(int l, int grp, int j) {
    if (grp == 0) return 1u << (5 + j);
    if (j >= 6) return 1u << (j - 4);                       // e2,e3,e4
    if (grp == 1) return mcol(l, 8 + j) & ~3u;              // h8..h13
    if (grp == 2) return j < 3 ? (mcol(l, 5 + j) & ~3u)     // h5..h7
                               : (mcol(l, 8 + j) & ~3u);    // h11..h13
    return mcol(l, 5 + j) & ~3u;                            // grp3: h5..h10
}

// register-space mask of gate K in group: mreg5(rmv) == full gate mask
template<int L, int GRP, int K> constexpr uint32_t rmv() {
    if constexpr (GRP == 0) {
        if constexpr (K < 2) return mcol(L, K);             // p0,p1 live in low2
        else return (4u << (K - 2)) | (mcol(L, K) & 3u);
    } else {
        return (4u << K) | (mcol(L, pbx(GRP) + K) & 3u);
    }
}
constexpr uint32_t mreg5(uint32_t r, uint32_t m0, uint32_t m1, uint32_t m2) {
    uint32_t M = r & 3u;
    if (r & 4u)  M ^= m0;
    if (r & 8u)  M ^= m1;
    if (r & 16u) M ^= m2;
    return M;
}
constexpr uint32_t sgnw32(uint32_t m0, uint32_t m1, uint32_t m2, uint32_t g) {
    uint32_t w = 0;
    for (uint32_t r = 0; r < 32; ++r)
        w |= (popb(mreg5(r, m0, m1, m2) & g) & 1u) << r;
    return w;
}
// tid-parity mask: bit j = parity(g & tb-basis_j)  (matches tb_of exactly)
constexpr uint32_t cgen(int l, int grp, uint32_t g) {
    uint32_t c = 0;
    for (int j = 0; j < 9; ++j)
        c |= (popb(g & tbb(l, grp, j)) & 1u) << j;
    return c;
}
// full 14-dim basis rank check per layout
constexpr bool rank14(int l, int grp) {
    uint32_t v[14];
    v[0] = 1u; v[1] = 2u;
    v[2] = mhvx(l, grp, 0); v[3] = mhvx(l, grp, 1); v[4] = mhvx(l, grp, 2);
    for (int j = 0; j < 9; ++j) v[5 + j] = tbb(l, grp, j);
    int rank = 0;
    for (int bit = 13; bit >= 0; --bit) {
        int piv = -1;
        for (int i = rank; i < 14; ++i) if ((v[i] >> bit) & 1) { piv = i; break; }
        if (piv < 0) continue;
        uint32_t t = v[piv]; v[piv] = v[rank]; v[rank] = t;
        for (int i = 0; i < 14; ++i) if (i != rank && ((v[i] >> bit) & 1)) v[i] ^= t;
        ++rank;
    }
    return rank == 14;
}

// runtime thread-base (quad-space element index, low2 = 0)
template<int L, int GRP>
__device__ __forceinline__ uint32_t tb_of(uint32_t tid) {
    if constexpr (GRP == 0) {
        return tid << 5;
    } else {
        constexpr uint32_t B[6] = {tbb(L, GRP, 0), tbb(L, GRP, 1), tbb(L, GRP, 2),
                                   tbb(L, GRP, 3), tbb(L, GRP, 4), tbb(L, GRP, 5)};
        uint32_t t = ((tid >> 6) & 7u) << 2;
#pragma unroll
        for (int j = 0; j < 6; ++j)
            t ^= (tid & (1u << j)) ? B[j] : 0u;
        return t;
    }
}

// ================= register-space gate (all compile-time) =================
template<uint32_t RM, uint32_t SG>
__device__ __forceinline__ void gate32(float (&rs)[32], float c, float svp) {
    constexpr uint32_t HB = 1u << msbit(RM);
#pragma unroll
    for (uint32_t r = 0; r < 32; ++r) {
        if ((r & HB) == 0u) {
            const float sv = ((SG >> r) & 1u) ? -svp : svp;   // compile-time select
            const float u = rs[r], v = rs[r ^ RM];
            const float t0 = sv * v;
            const float t1 = sv * u;
            rs[r]      = fmaf(c, u, -t0);   // side0' = c*s0 - s*s1
            rs[r ^ RM] = fmaf(c, v,  t1);   // side1' = c*s1 + s*s0
        }
    }
}

template<int L, int GRP, int K>
__device__ __forceinline__ void gates_rec(float (&rs)[32], const float* __restrict__ cst,
                                          const float* __restrict__ snt, int tid) {
    if constexpr (K < ngates<GRP>()) {
        constexpr int p = pbx(GRP) + K;
        constexpr uint32_t g  = grow(L, p);
        constexpr uint32_t RM = rmv<L, GRP, K>();
        constexpr uint32_t SG = sgnw32(mhv<L,GRP,0>(), mhv<L,GRP,1>(), mhv<L,GRP,2>(), g);
        constexpr uint32_t CG = cgen(L, GRP, g);
        constexpr int widx = (L - 1) * NQ + (13 - p);
        const float c = cst[widx];
        const float s = snt[widx];
        const float svp = (__popc((uint32_t)tid & CG) & 1) ? -s : s;
        gate32<RM, SG>(rs, c, svp);
        gates_rec<L, GRP, K + 1>(rs, cst, snt, tid);
    }
}

template<int L, int GRP>
__device__ __forceinline__ void run_gates(float (&rs)[32], const float* __restrict__ cst,
                                          const float* __restrict__ snt, int tid) {
    static_assert(rank14(L, GRP), "basis rank");
    gates_rec<L, GRP, 0>(rs, cst, snt, tid);
}

template<int L, int GRP, bool WR>
__device__ __forceinline__ void lds_io(float (&rs)[32], float* st, int tid) {
    constexpr uint32_t m0 = mhv<L,GRP,0>(), m1 = mhv<L,GRP,1>(), m2 = mhv<L,GRP,2>();
    const uint32_t ptw = PIW(tb_of<L, GRP>((uint32_t)tid));
#pragma unroll
    for (uint32_t gq = 0; gq < 8; ++gq) {
        const uint32_t K = ((gq & 1) ? m0 : 0u) ^ ((gq & 2) ? m1 : 0u) ^ ((gq & 4) ? m2 : 0u);
        const uint32_t a = ptw ^ PIW(K);                        // PIW(K) folds (XOR-linear)
        if constexpr (WR) *reinterpret_cast<float4*>(st + a) = *reinterpret_cast<const float4*>(&rs[gq * 4]);
        else *reinterpret_cast<float4*>(&rs[gq * 4]) = *reinterpret_cast<const float4*>(st + a);
    }
}

// One phase: read own set, gates, write own set (same addrs).
// SYNC=true  -> cross-wave transition follows: block barrier.
// SYNC=false -> wave-local transition follows (G1->G2, G2->G3): the next
//   read touches only quads THIS wave just wrote (wave-closure, rank-9 h-span);
//   per-wave in-order DS + lgkmcnt fence suffice — no block barrier.
template<int L, int GRP, bool SYNC>
__device__ __forceinline__ void phase(float (&rs)[32], float* st,
        const float* __restrict__ cst, const float* __restrict__ snt, int tid) {
    lds_io<L, GRP, false>(rs, st, tid);
    run_gates<L, GRP>(rs, cst, snt, tid);
    lds_io<L, GRP, true>(rs, st, tid);
    if constexpr (SYNC) __syncthreads();
    else asm volatile("s_waitcnt lgkmcnt(0)" ::: "memory");
}

// ================= prepass: min/scale + gate cos/sin tables =================
__global__ __launch_bounds__(256) void qs_norm_kernel(const float* __restrict__ x,
                                                      const float* __restrict__ w,
                                                      float* __restrict__ ws) {
    const int q = blockIdx.x;
    const int tid = threadIdx.x;
    float mn = 3.0e38f, mx = -3.0e38f;
    for (int r = tid; r < NBATCH; r += 256) {
        const float v = x[r * NQ + q];
        mn = fminf(mn, v);
        mx = fmaxf(mx, v);
    }
#pragma unroll
    for (int off = 32; off > 0; off >>= 1) {
        mn = fminf(mn, __shfl_down(mn, off));
        mx = fmaxf(mx, __shfl_down(mx, off));
    }
    __shared__ float smn[4], smx[4];
    const int wid = tid >> 6, lane = tid & 63;
    if (lane == 0) { smn[wid] = mn; smx[wid] = mx; }
    __syncthreads();
    if (tid == 0) {
        mn = fminf(fminf(smn[0], smn[1]), fminf(smn[2], smn[3]));
        mx = fmaxf(fmaxf(smx[0], smx[1]), fmaxf(smx[2], smx[3]));
        ws[q] = mn;
        ws[NQ + q] = PI_F / (mx - mn + 1e-8f);
    }
    if (blockIdx.x == 0) {
        for (int t = tid; t < (NL - 1) * NQ; t += 256) {
            const float h = 0.5f * w[NQ + t];
            ws[32 + t]  = cosf(h);
            ws[112 + t] = sinf(h);
        }
    }
}

// ================= main: one block (512 threads) per batch element =================
__global__ __launch_bounds__(BLOCK, 4) void qs_main_kernel(
        const float* __restrict__ x, const float* __restrict__ w,
        const float* __restrict__ nrm, const float* __restrict__ cst,
        const float* __restrict__ snt, float* __restrict__ out) {
    __shared__ __align__(16) float st[DIM];
    __shared__ float sciL[NQ], ssiL[NQ];
    __shared__ float red0[8], red1[8];
    const int tid = threadIdx.x;
    const int b = blockIdx.x;

    // merged encoding + layer-0 angles, once per block (broadcast via LDS)
    if (tid < NQ) {
        const float ang = (x[b * NQ + tid] - nrm[tid]) * nrm[NQ + tid] + w[tid];
        const float h = 0.5f * ang;
        sciL[tid] = cosf(h);
        ssiL[tid] = sinf(h);
    }
    __syncthreads();

    // product state directly in registers, layout (1,0):
    // element i = (tid<<5) ^ mreg5(r, mhv(1,0,*)); element bit b <-> qubit 13-b
    float H = 1.0f;
#pragma unroll
    for (int j = 0; j < 9; ++j) H *= ((tid >> j) & 1) ? ssiL[8 - j] : sciL[8 - j];
    float A4[4], HB8[8];
#pragma unroll
    for (int a = 0; a < 4; ++a)
        A4[a] = ((a & 1) ? ssiL[13] : sciL[13]) * ((a & 2) ? ssiL[12] : sciL[12]);
#pragma unroll
    for (int rh = 0; rh < 8; ++rh) {
        const uint32_t Mhi = ((rh & 1) ? 4u : 0u) ^ ((rh & 2) ? 12u : 0u) ^ ((rh & 4) ? 24u : 0u);
        HB8[rh] = H * ((Mhi >> 2) & 1 ? ssiL[11] : sciL[11]) *
                      ((Mhi >> 3) & 1 ? ssiL[10] : sciL[10]) *
                      ((Mhi >> 4) & 1 ? ssiL[9]  : sciL[9]);
    }
    alignas(16) float rs[32];
#pragma unroll
    for (int r = 0; r < 32; ++r) rs[r] = A4[r & 3] * HB8[r >> 2];

    // 20 phases; 9 block barriers (cross-wave) + 10 wave-local transitions
    run_gates<1, 0>(rs, cst, snt, tid); lds_io<1, 0, true>(rs, st, tid); __syncthreads();
    phase<1, 1, false>(rs, st, cst, snt, tid);
    phase<1, 2, false>(rs, st, cst, snt, tid);
    phase<1, 3, true >(rs, st, cst, snt, tid);
    phase<2, 0, true >(rs, st, cst, snt, tid);
    phase<2, 1, false>(rs, st, cst, snt, tid);
    phase<2, 2, false>(rs, st, cst, snt, tid);
    phase<2, 3, true >(rs, st, cst, snt, tid);
    phase<3, 0, true >(rs, st, cst, snt, tid);
    phase<3, 1, false>(rs, st, cst, snt, tid);
    phase<3, 2, false>(rs, st, cst, snt, tid);
    phase<3, 3, true >(rs, st, cst, snt, tid);
    phase<4, 0, true >(rs, st, cst, snt, tid);
    phase<4, 1, false>(rs, st, cst, snt, tid);
    phase<4, 2, false>(rs, st, cst, snt, tid);
    phase<4, 3, true >(rs, st, cst, snt, tid);
    phase<5, 0, true >(rs, st, cst, snt, tid);
    phase<5, 1, false>(rs, st, cst, snt, tid);
    phase<5, 2, false>(rs, st, cst, snt, tid);
    lds_io<5, 3, false>(rs, st, tid);
    run_gates<5, 3>(rs, cst, snt, tid);

    // expectations in-register: gout = e13/e12 (rows 13/12 of U^6).
    // G3 tb spans h5..h10 (bits<=10) + e2..e4 -> no bits 12/13 from tb;
    // sign is compile-time per register.
    constexpr uint32_t f0 = mhv<5,3,0>(), f1 = mhv<5,3,1>(), f2 = mhv<5,3,2>();
    float e0 = 0.0f, e1 = 0.0f;
#pragma unroll
    for (uint32_t r = 0; r < 32; ++r) {
        const uint32_t M = mreg5(r, f0, f1, f2);
        const float v = rs[r];
        e0 = fmaf(v, ((M >> 13) & 1u) ? -v : v, e0);
        e1 = fmaf(v, ((M >> 12) & 1u) ? -v : v, e1);
    }
#pragma unroll
    for (int off = 32; off > 0; off >>= 1) {
        e0 += __shfl_down(e0, off);
        e1 += __shfl_down(e1, off);
    }
    const int wid = tid >> 6, lane = tid & 63;
    if (lane == 0) { red0[wid] = e0; red1[wid] = e1; }
    __syncthreads();
    if (tid == 0) {
        float a0 = 0.0f, a1 = 0.0f;
#pragma unroll
        for (int i = 0; i < 8; ++i) { a0 += red0[i]; a1 += red1[i]; }
        out[b * 2 + 0] = a0;
        out[b * 2 + 1] = a1;
    }
}

extern "C" void kernel_launch(void* const* d_in, const int* in_sizes, int n_in,
                              void* d_out, int out_size, void* d_ws, size_t ws_size,
                              hipStream_t stream) {
    const float* x = (const float*)d_in[0];   // (1024, 14) f32
    const float* w = (const float*)d_in[1];   // (6, 14) f32
    float* out = (float*)d_out;               // (1024, 2) f32
    float* ws = (float*)d_ws;                 // [0..27] min/scale, [32..101] cos, [112..181] sin

    qs_norm_kernel<<<NQ, 256, 0, stream>>>(x, w, ws);
    qs_main_kernel<<<NBATCH, BLOCK, 0, stream>>>(x, w, ws, ws + 32, ws + 112, out);
}

// Round 10
// 71.507 us; speedup vs baseline: 1.0433x; 1.0433x over previous
//
#include <hip/hip_runtime.h>
#include <stdint.h>

#define NQ 14
#define DIM 16384
#define NL 6
#define NBATCH 1024
#define PI_F 3.14159265358979323846f
#define BLOCK 512

// ================= constexpr GF(2) circuit algebra =================
// Verified end-to-end (rounds 2/5/7: absmax 0.0).  CNOT chain = I+S.
// After l chains, gate on bit p pairs i with i^mcol(l,p); side-0 selected by
// parity(i & grow(l,p)).  Lucas: C(l,k) odd iff (k & ~l)==0.
constexpr uint32_t mcol(int l, int p) {          // column p of (I+S)^l
    uint32_t m = 0;
    for (int k = 0; k <= p; ++k) if ((k & ~l) == 0) m ^= 1u << (p - k);
    return m;
}
constexpr uint32_t grow(int l, int p) {          // row p of U^l = (I+S)^(16-l)
    uint32_t g = 0;
    const int e = 16 - l;
    for (int k = 0; k + p < NQ; ++k) if ((k & ~e) == 0) g ^= 1u << (p + k);
    return g;
}
constexpr uint32_t popb(uint32_t x) { uint32_t c = 0; while (x) { c += x & 1u; x >>= 1; } return c; }
constexpr int msbit(uint32_t m) { int b = 0; while (m >> (b + 1)) ++b; return b; }
// Bank swizzle on ELEMENT index (bf16 u32-addr = elem>>1, bank = u32 bits 0..4
// = elem bits 1..5): fold elem bits 6..8 -> 2..4 and bit 9 -> 5. XOR-linear,
// bijective (triangular), preserves low-2 bits (quad/pair structure).
constexpr uint32_t PB(uint32_t x) {
    return x ^ (((x >> 6) & 7u) << 2) ^ (((x >> 9) & 1u) << 5);
}

// 4 groups per layer: p ranges {0..4}, {5..7}, {8..10}, {11..13}
constexpr int pbx(int grp) { return grp == 0 ? 0 : (grp == 1 ? 5 : (grp == 2 ? 8 : 11)); }
template<int GRP> constexpr int ngates() { return GRP == 0 ? 5 : 3; }

// phase basis: {e0,e1} + 3 hi vectors (4-aligned, = gate-mask hi parts)
template<int L, int GRP, int J> constexpr uint32_t mhv() {
    if constexpr (GRP == 0) return mcol(L, 2 + J) & ~3u;          // gates p2,p3,p4
    else return mcol(L, pbx(GRP) + J) & ~3u;
}
// register-space mask: mreg5(rmv) == full gate mask (register bit2..4 = m0..m2)
template<int L, int GRP, int K> constexpr uint32_t rmv() {
    if constexpr (GRP == 0) {
        if constexpr (K < 2) return mcol(L, K);                   // p0,p1 live in low2
        else return (4u << (K - 2)) | (mcol(L, K) & 3u);
    } else {
        return (4u << K) | (mcol(L, pbx(GRP) + K) & 3u);
    }
}
constexpr uint32_t mreg5(uint32_t r, uint32_t m0, uint32_t m1, uint32_t m2) {
    uint32_t M = r & 3u;
    if (r & 4u)  M ^= m0;
    if (r & 8u)  M ^= m1;
    if (r & 16u) M ^= m2;
    return M;
}
constexpr uint32_t sgnw32(uint32_t m0, uint32_t m1, uint32_t m2, uint32_t g) {
    uint32_t w = 0;
    for (uint32_t r = 0; r < 32; ++r)
        w |= (popb(mreg5(r, m0, m1, m2) & g) & 1u) << r;
    return w;
}
// tid-parity mask: comp units are {e2..e13} minus the 3 pivot bits {pbase..pbase+2}
template<int GRP> constexpr uint32_t cg_of(uint32_t g) {
    if constexpr (GRP == 0)      return (g >> 5) & 0x1FFu;                          // units e5..e13
    else if constexpr (GRP == 1) return ((g >> 2) & 7u) | (((g >> 8) & 0x3Fu) << 3); // e2..e4,e8..e13
    else if constexpr (GRP == 2) return ((g >> 2) & 0x3Fu) | (((g >> 11) & 7u) << 6);// e2..e7,e11..e13
    else                         return (g >> 2) & 0x1FFu;                          // e2..e10
}
constexpr bool indep5(uint32_t a, uint32_t b, uint32_t c) {
    uint32_t v[5] = {1u, 2u, a, b, c};
    int rank = 0;
    for (int bit = 13; bit >= 0; --bit) {
        int piv = -1;
        for (int i = rank; i < 5; ++i) if ((v[i] >> bit) & 1) { piv = i; break; }
        if (piv < 0) continue;
        uint32_t t = v[piv]; v[piv] = v[rank]; v[rank] = t;
        for (int i = 0; i < 5; ++i) if (i != rank && ((v[i] >> bit) & 1)) v[i] ^= t;
        ++rank;
    }
    return rank == 5;
}

// RAW thread-base element index (un-swizzled); 9 tid bits -> comp unit bits
template<int GRP> __device__ __forceinline__ uint32_t tb_of(uint32_t tid) {
    if constexpr (GRP == 0)      return tid << 5;
    else if constexpr (GRP == 1) return ((tid & 7u) << 2) | ((tid >> 3) << 8);
    else if constexpr (GRP == 2) return ((tid & 63u) << 2) | ((tid >> 6) << 11);
    else                         return tid << 2;
}

// ================= bf16 pack/unpack (state transit precision) =================
// pack: v_cvt_pk_bf16_f32 (RNE, unbiased — truncation would drift ~0.2%/trip).
// unpack: exact (bf16 -> f32 is lossless via shift/and).
__device__ __forceinline__ uint32_t pk2(float lo, float hi) {
    uint32_t r;
    asm("v_cvt_pk_bf16_f32 %0, %1, %2" : "=v"(r) : "v"(lo), "v"(hi));
    return r;
}
__device__ __forceinline__ void unpk2(uint32_t u, float& lo, float& hi) {
    lo = __uint_as_float(u << 16);
    hi = __uint_as_float(u & 0xffff0000u);
}

// ================= register-space gate (all compile-time) =================
template<uint32_t RM, uint32_t SG>
__device__ __forceinline__ void gate32(float (&rs)[32], float c, float svp) {
    constexpr uint32_t HB = 1u << msbit(RM);
#pragma unroll
    for (uint32_t r = 0; r < 32; ++r) {
        if ((r & HB) == 0u) {
            const float sv = ((SG >> r) & 1u) ? -svp : svp;   // compile-time select
            const float u = rs[r], v = rs[r ^ RM];
            const float t0 = sv * v;
            const float t1 = sv * u;
            rs[r]      = fmaf(c, u, -t0);   // side0' = c*s0 - s*s1
            rs[r ^ RM] = fmaf(c, v,  t1);   // side1' = c*s1 + s*s0
        }
    }
}

template<int L, int GRP, int K>
__device__ __forceinline__ void gates_rec(float (&rs)[32], const float* __restrict__ cst,
                                          const float* __restrict__ snt, int tid) {
    if constexpr (K < ngates<GRP>()) {
        constexpr int p = pbx(GRP) + K;
        constexpr uint32_t g  = grow(L, p);
        constexpr uint32_t RM = rmv<L, GRP, K>();
        constexpr uint32_t SG = sgnw32(mhv<L,GRP,0>(), mhv<L,GRP,1>(), mhv<L,GRP,2>(), g);
        constexpr uint32_t CG = cg_of<GRP>(g);
        constexpr int widx = (L - 1) * NQ + (13 - p);
        const float c = cst[widx];
        const float s = snt[widx];
        const float svp = (__popc((uint32_t)tid & CG) & 1) ? -s : s;
        gate32<RM, SG>(rs, c, svp);
        gates_rec<L, GRP, K + 1>(rs, cst, snt, tid);
    }
}

template<int L, int GRP>
__device__ __forceinline__ void run_gates(float (&rs)[32], const float* __restrict__ cst,
                                          const float* __restrict__ snt, int tid) {
    static_assert(indep5(mhv<L,GRP,0>(), mhv<L,GRP,1>(), mhv<L,GRP,2>()), "basis rank");
    gates_rec<L, GRP, 0>(rs, cst, snt, tid);
}

// LDS IO: 8 quads x (2 x bf16x2 = uint2, 8B).  u32 addr = PB(elem)>>1 (even).
template<int L, int GRP, bool WR>
__device__ __forceinline__ void lds_io(float (&rs)[32], uint32_t* st, int tid) {
    constexpr uint32_t m0 = mhv<L,GRP,0>(), m1 = mhv<L,GRP,1>(), m2 = mhv<L,GRP,2>();
    const uint32_t ptw = PB(tb_of<GRP>((uint32_t)tid));
#pragma unroll
    for (uint32_t gq = 0; gq < 8; ++gq) {
        const uint32_t K = ((gq & 1) ? m0 : 0u) ^ ((gq & 2) ? m1 : 0u) ^ ((gq & 4) ? m2 : 0u);
        const uint32_t a = (ptw ^ PB(K)) >> 1;        // PB(K) folds (PB is XOR-linear)
        if constexpr (WR) {
            uint2 v;
            v.x = pk2(rs[gq * 4 + 0], rs[gq * 4 + 1]);
            v.y = pk2(rs[gq * 4 + 2], rs[gq * 4 + 3]);
            *reinterpret_cast<uint2*>(st + a) = v;
        } else {
            const uint2 v = *reinterpret_cast<const uint2*>(st + a);
            unpk2(v.x, rs[gq * 4 + 0], rs[gq * 4 + 1]);
            unpk2(v.y, rs[gq * 4 + 2], rs[gq * 4 + 3]);
        }
    }
}

template<int L, int GRP>
__device__ __forceinline__ void mid_phase(float (&rs)[32], uint32_t* st,
        const float* __restrict__ cst, const float* __restrict__ snt, int tid) {
    lds_io<L, GRP, false>(rs, st, tid);
    run_gates<L, GRP>(rs, cst, snt, tid);
    lds_io<L, GRP, true>(rs, st, tid);
    __syncthreads();
}

// ================= prepass: min/scale + gate cos/sin tables =================
__global__ __launch_bounds__(256) void qs_norm_kernel(const float* __restrict__ x,
                                                      const float* __restrict__ w,
                                                      float* __restrict__ ws) {
    const int q = blockIdx.x;
    const int tid = threadIdx.x;
    float mn = 3.0e38f, mx = -3.0e38f;
    for (int r = tid; r < NBATCH; r += 256) {
        const float v = x[r * NQ + q];
        mn = fminf(mn, v);
        mx = fmaxf(mx, v);
    }
#pragma unroll
    for (int off = 32; off > 0; off >>= 1) {
        mn = fminf(mn, __shfl_down(mn, off));
        mx = fmaxf(mx, __shfl_down(mx, off));
    }
    __shared__ float smn[4], smx[4];
    const int wid = tid >> 6, lane = tid & 63;
    if (lane == 0) { smn[wid] = mn; smx[wid] = mx; }
    __syncthreads();
    if (tid == 0) {
        mn = fminf(fminf(smn[0], smn[1]), fminf(smn[2], smn[3]));
        mx = fmaxf(fmaxf(smx[0], smx[1]), fmaxf(smx[2], smx[3]));
        ws[q] = mn;
        ws[NQ + q] = PI_F / (mx - mn + 1e-8f);
    }
    if (blockIdx.x == 0) {
        for (int t = tid; t < (NL - 1) * NQ; t += 256) {
            const float h = 0.5f * w[NQ + t];
            ws[32 + t]  = cosf(h);
            ws[112 + t] = sinf(h);
        }
    }
}

// ================= main: one block (512 threads) per batch element =================
__global__ __launch_bounds__(BLOCK, 8) void qs_main_kernel(
        const float* __restrict__ x, const float* __restrict__ w,
        const float* __restrict__ nrm, const float* __restrict__ cst,
        const float* __restrict__ snt, float* __restrict__ out) {
    __shared__ __align__(16) uint32_t st[DIM / 2];    // 32 KB bf16 state
    __shared__ float sciL[NQ], ssiL[NQ];
    __shared__ float red0[8], red1[8];
    const int tid = threadIdx.x;
    const int b = blockIdx.x;

    // merged encoding + layer-0 angles, once per block (broadcast via LDS)
    if (tid < NQ) {
        const float ang = (x[b * NQ + tid] - nrm[tid]) * nrm[NQ + tid] + w[tid];
        const float h = 0.5f * ang;
        sciL[tid] = cosf(h);
        ssiL[tid] = sinf(h);
    }
    __syncthreads();

    // product state directly in registers, layout (1,0):
    // element i = (tid<<5) ^ mreg5(r, mhv(1,0,*)); element bit b <-> qubit 13-b
    float H = 1.0f;
#pragma unroll
    for (int j = 0; j < 9; ++j) H *= ((tid >> j) & 1) ? ssiL[8 - j] : sciL[8 - j];
    float A4[4], HB8[8];
#pragma unroll
    for (int a = 0; a < 4; ++a)
        A4[a] = ((a & 1) ? ssiL[13] : sciL[13]) * ((a & 2) ? ssiL[12] : sciL[12]);
#pragma unroll
    for (int rh = 0; rh < 8; ++rh) {
        const uint32_t Mhi = ((rh & 1) ? 4u : 0u) ^ ((rh & 2) ? 12u : 0u) ^ ((rh & 4) ? 24u : 0u);
        HB8[rh] = H * ((Mhi >> 2) & 1 ? ssiL[11] : sciL[11]) *
                      ((Mhi >> 3) & 1 ? ssiL[10] : sciL[10]) *
                      ((Mhi >> 4) & 1 ? ssiL[9]  : sciL[9]);
    }
    alignas(16) float rs[32];
#pragma unroll
    for (int r = 0; r < 32; ++r) rs[r] = A4[r & 3] * HB8[r >> 2];

    // 20 phases, 4 per layer; first has no read, last has no write
    run_gates<1, 0>(rs, cst, snt, tid); lds_io<1, 0, true>(rs, st, tid); __syncthreads();
    mid_phase<1, 1>(rs, st, cst, snt, tid);
    mid_phase<1, 2>(rs, st, cst, snt, tid);
    mid_phase<1, 3>(rs, st, cst, snt, tid);
    mid_phase<2, 0>(rs, st, cst, snt, tid);
    mid_phase<2, 1>(rs, st, cst, snt, tid);
    mid_phase<2, 2>(rs, st, cst, snt, tid);
    mid_phase<2, 3>(rs, st, cst, snt, tid);
    mid_phase<3, 0>(rs, st, cst, snt, tid);
    mid_phase<3, 1>(rs, st, cst, snt, tid);
    mid_phase<3, 2>(rs, st, cst, snt, tid);
    mid_phase<3, 3>(rs, st, cst, snt, tid);
    mid_phase<4, 0>(rs, st, cst, snt, tid);
    mid_phase<4, 1>(rs, st, cst, snt, tid);
    mid_phase<4, 2>(rs, st, cst, snt, tid);
    mid_phase<4, 3>(rs, st, cst, snt, tid);
    mid_phase<5, 0>(rs, st, cst, snt, tid);
    mid_phase<5, 1>(rs, st, cst, snt, tid);
    mid_phase<5, 2>(rs, st, cst, snt, tid);
    lds_io<5, 3, false>(rs, st, tid);
    run_gates<5, 3>(rs, cst, snt, tid);

    // expectations in-register: gout = e13/e12 (rows 13/12 of U^6);
    // layout (5,3) thread-base has no bits >=11 in hi masks -> compile-time sign
    constexpr uint32_t f0 = mhv<5,3,0>(), f1 = mhv<5,3,1>(), f2 = mhv<5,3,2>();
    float e0 = 0.0f, e1 = 0.0f;
#pragma unroll
    for (uint32_t r = 0; r < 32; ++r) {
        const uint32_t M = mreg5(r, f0, f1, f2);
        const float v = rs[r];
        e0 = fmaf(v, ((M >> 13) & 1u) ? -v : v, e0);
        e1 = fmaf(v, ((M >> 12) & 1u) ? -v : v, e1);
    }
#pragma unroll
    for (int off = 32; off > 0; off >>= 1) {
        e0 += __shfl_down(e0, off);
        e1 += __shfl_down(e1, off);
    }
    const int wid = tid >> 6, lane = tid & 63;
    if (lane == 0) { red0[wid] = e0; red1[wid] = e1; }
    __syncthreads();
    if (tid == 0) {
        float a0 = 0.0f, a1 = 0.0f;
#pragma unroll
        for (int i = 0; i < 8; ++i) { a0 += red0[i]; a1 += red1[i]; }
        out[b * 2 + 0] = a0;
        out[b * 2 + 1] = a1;
    }
}

extern "C" void kernel_launch(void* const* d_in, const int* in_sizes, int n_in,
                              void* d_out, int out_size, void* d_ws, size_t ws_size,
                              hipStream_t stream) {
    const float* x = (const float*)d_in[0];   // (1024, 14) f32
    const float* w = (const float*)d_in[1];   // (6, 14) f32
    float* out = (float*)d_out;               // (1024, 2) f32
    float* ws = (float*)d_ws;                 // [0..27] min/scale, [32..101] cos, [112..181] sin

    qs_norm_kernel<<<NQ, 256, 0, stream>>>(x, w, ws);
    qs_main_kernel<<<NBATCH, BLOCK, 0, stream>>>(x, w, ws, ws + 32, ws + 112, out);
}